// Round 1
// baseline (5766.650 us; speedup 1.0000x reference)
//
#include <hip/hip_runtime.h>

// ATAE-LSTM fused pipeline for MI355X (gfx950).
// V=50000, D=512, B=64, L=512, A=4, 4D=2048.

using f32x4  = __attribute__((ext_vector_type(4))) float;
using s16x4  = __attribute__((ext_vector_type(4))) short;
using bf16x8 = __attribute__((ext_vector_type(8))) __bf16;

#define LOG2E 1.4426950408889634f

__device__ __forceinline__ float b2f(short s) {
  union { unsigned u; float f; } c;
  c.u = ((unsigned)(unsigned short)s) << 16;
  return c.f;
}
__device__ __forceinline__ short f2bf(float f) {
  union { float f; unsigned u; } c; c.f = f;
  unsigned r = (c.u + 0x7FFFu + ((c.u >> 16) & 1u)) >> 16;
  return (short)(unsigned short)r;
}
__device__ __forceinline__ float sigm_(float x) {
  float e = __builtin_amdgcn_exp2f(-x * LOG2E);
  return __builtin_amdgcn_rcpf(1.0f + e);
}
__device__ __forceinline__ float tanh_(float x) {
  float e = __builtin_amdgcn_exp2f(x * (2.0f * LOG2E));
  return 1.0f - 2.0f * __builtin_amdgcn_rcpf(1.0f + e);
}

// ---------------------------------------------------------------------------
// K1a: aspect embedding average (sum over ALL A entries / aspect_lengths),
//      written to ws and to d_out's third-output region. Also zeroes flags.
__global__ void k_asp(const int* __restrict__ aspect, const int* __restrict__ alen,
                      const float* __restrict__ emb, float* __restrict__ asp_emb,
                      float* __restrict__ out_asp, int* __restrict__ flags) {
  int b = blockIdx.x;          // 64
  int t = threadIdx.x;         // 128, 4 floats each
  if (b == 0 && t < 64) flags[t] = 0;
  f32x4 s = {0.f, 0.f, 0.f, 0.f};
  #pragma unroll
  for (int a = 0; a < 4; ++a) {
    int idx = aspect[b * 4 + a];
    s += *(const f32x4*)(emb + (size_t)idx * 512 + t * 4);
  }
  float inv = 1.0f / (float)alen[b];
  s[0] *= inv; s[1] *= inv; s[2] *= inv; s[3] *= inv;
  *(f32x4*)(asp_emb + (size_t)b * 512 + t * 4) = s;
  *(f32x4*)(out_asp + (size_t)b * 512 + t * 4) = s;
}

// ---------------------------------------------------------------------------
// K1b: pack W_ih (word half) and W_hh rows into block-interleaved gate order,
// bf16.  Packed index P: j=P>>5 (block), u=(P>>2)&7 (unit), gate=P&3.
// Source gate row gr = gate*512 + j*8 + u.
__global__ void k_pack(const float* __restrict__ W_ih, const float* __restrict__ W_hh,
                       short* __restrict__ W1p, short* __restrict__ Whp) {
  int P = blockIdx.x;          // 2048
  int t = threadIdx.x;         // 128, 4 elems each
  int gr = (P & 3) * 512 + (P >> 5) * 8 + ((P >> 2) & 7);
  f32x4 w1 = *(const f32x4*)(W_ih + (size_t)gr * 1024 + t * 4);
  f32x4 wh = *(const f32x4*)(W_hh + (size_t)gr * 512 + t * 4);
  s16x4 o1, oh;
  #pragma unroll
  for (int i = 0; i < 4; ++i) { o1[i] = f2bf(w1[i]); oh[i] = f2bf(wh[i]); }
  *(s16x4*)(W1p + (size_t)P * 512 + t * 4) = o1;
  *(s16x4*)(Whp + (size_t)P * 512 + t * 4) = oh;
}

// ---------------------------------------------------------------------------
// K1c: asp_contrib[b][P] = asp_emb[b] . W_ih[gr][512:1024] + b_ih[gr] + b_hh[gr]
__global__ void k_aspc(const float* __restrict__ asp_emb, const float* __restrict__ W_ih,
                       const float* __restrict__ b_ih, const float* __restrict__ b_hh,
                       float* __restrict__ aspc) {
  int tid = threadIdx.x;                 // 256
  int P = blockIdx.x * 32 + (tid >> 3);  // 64 blocks
  int gr = (P & 3) * 512 + (P >> 5) * 8 + ((P >> 2) & 7);
  const float* wrow = W_ih + (size_t)gr * 1024 + 512;
  float bias = b_ih[gr] + b_hh[gr];
  int b0 = (tid & 7) * 8;
  float a[8];
  #pragma unroll
  for (int i = 0; i < 8; ++i) a[i] = 0.f;
  for (int k = 0; k < 512; k += 4) {
    f32x4 wv = *(const f32x4*)(wrow + k);
    #pragma unroll
    for (int bb = 0; bb < 8; ++bb) {
      f32x4 av = *(const f32x4*)(asp_emb + (size_t)(b0 + bb) * 512 + k);
      a[bb] += wv[0] * av[0] + wv[1] * av[1] + wv[2] * av[2] + wv[3] * av[3];
    }
  }
  #pragma unroll
  for (int bb = 0; bb < 8; ++bb) aspc[(size_t)(b0 + bb) * 2048 + P] = a[bb] + bias;
}

// ---------------------------------------------------------------------------
// K2: word embedding gather -> bf16, zero masked rows.
__global__ void k_gather(const int* __restrict__ X, const int* __restrict__ xlen,
                         const float* __restrict__ emb, short* __restrict__ word) {
  int g = blockIdx.x * 256 + threadIdx.x;  // 16384 blocks
  int row = g >> 7;                        // 128 threads per row
  int k4 = (g & 127) << 2;
  int b = row >> 9, l = row & 511;
  s16x4 o;
  if (l < xlen[b]) {
    int idx = X[row];
    f32x4 v = *(const f32x4*)(emb + (size_t)idx * 512 + k4);
    o[0] = f2bf(v[0]); o[1] = f2bf(v[1]); o[2] = f2bf(v[2]); o[3] = f2bf(v[3]);
  } else {
    o[0] = 0; o[1] = 0; o[2] = 0; o[3] = 0;
  }
  *(s16x4*)(word + (size_t)row * 512 + k4) = o;
}

// ---------------------------------------------------------------------------
// K3: GEMM  xproj[(b,l)][P] = word[(b,l),:] . W1p[P,:] + aspc[b][P]   (bf16 out)
// 128x128 tile, BK=64, 4 waves (64x64 each), st-16x32 LDS swizzle,
// global_load_lds width-16 staging, masked row-tiles skipped.
__global__ __launch_bounds__(256)
void k_gemm(const short* __restrict__ A, const short* __restrict__ B,
            const float* __restrict__ aspc, const int* __restrict__ xlen,
            short* __restrict__ C) {
  __shared__ char smem[65536];  // A0 A1 B0 B1, 16KB each
  const int rt = blockIdx.x, ct = blockIdx.y;
  const int b = rt >> 2;
  if (xlen[b] <= ((rt & 3) << 7)) return;  // fully-masked row tile
  const int tid = threadIdx.x;
  const int w = tid >> 6, lane = tid & 63;
  const int lr = lane & 15, lg = lane >> 4;
  const int wr = (w & 1) * 64, wc = (w >> 1) * 64;
  const char* Ab = (const char*)(A + (size_t)rt * 128 * 512);
  const char* Bb = (const char*)(B + (size_t)ct * 128 * 512);

  f32x4 acc[4][4];
  #pragma unroll
  for (int mi = 0; mi < 4; ++mi)
    #pragma unroll
    for (int ni = 0; ni < 4; ++ni) acc[mi][ni] = {0.f, 0.f, 0.f, 0.f};

  auto stage = [&](int kt, int buf) {
    #pragma unroll
    for (int p = 0; p < 4; ++p) {
      int dbase = w * 1024 + p * 4096;   // wave-uniform LDS base
      int d = dbase + (lane << 4);
      int row = d >> 7;
      int kb = (d & 127) ^ (((d >> 9) & 1) << 5);  // pre-swizzled source
      __builtin_amdgcn_global_load_lds(
          (const __attribute__((address_space(1))) unsigned*)(Ab + (size_t)row * 1024 + kt * 128 + kb),
          (__attribute__((address_space(3))) unsigned*)(smem + buf * 16384 + dbase), 16, 0, 0);
      __builtin_amdgcn_global_load_lds(
          (const __attribute__((address_space(1))) unsigned*)(Bb + (size_t)row * 1024 + kt * 128 + kb),
          (__attribute__((address_space(3))) unsigned*)(smem + 32768 + buf * 16384 + dbase), 16, 0, 0);
    }
  };

  stage(0, 0);
  __syncthreads();
  #pragma unroll 1
  for (int kt = 0; kt < 8; ++kt) {
    int cur = kt & 1;
    if (kt < 7) stage(kt + 1, cur ^ 1);
    const char* sAc = smem + cur * 16384;
    const char* sBc = smem + 32768 + cur * 16384;
    #pragma unroll
    for (int kk = 0; kk < 2; ++kk) {
      bf16x8 af[4], bfr[4];
      #pragma unroll
      for (int mi = 0; mi < 4; ++mi) {
        int lin = (wr + mi * 16 + lr) * 128 + kk * 64 + lg * 16;
        af[mi] = *(const bf16x8*)(sAc + (lin ^ (((lin >> 9) & 1) << 5)));
      }
      #pragma unroll
      for (int ni = 0; ni < 4; ++ni) {
        int lin = (wc + ni * 16 + lr) * 128 + kk * 64 + lg * 16;
        bfr[ni] = *(const bf16x8*)(sBc + (lin ^ (((lin >> 9) & 1) << 5)));
      }
      #pragma unroll
      for (int mi = 0; mi < 4; ++mi)
        #pragma unroll
        for (int ni = 0; ni < 4; ++ni)
          acc[mi][ni] = __builtin_amdgcn_mfma_f32_16x16x32_bf16(af[mi], bfr[ni], acc[mi][ni], 0, 0, 0);
    }
    __syncthreads();
  }

  const int colb = ct * 128 + wc;
  float cb[4];
  #pragma unroll
  for (int ni = 0; ni < 4; ++ni) cb[ni] = aspc[(size_t)b * 2048 + colb + ni * 16 + lr];
  #pragma unroll
  for (int mi = 0; mi < 4; ++mi) {
    const int row0 = rt * 128 + wr + mi * 16 + lg * 4;
    #pragma unroll
    for (int r = 0; r < 4; ++r) {
      short* crow = C + (size_t)(row0 + r) * 2048 + colb + lr;
      #pragma unroll
      for (int ni = 0; ni < 4; ++ni)
        crow[ni * 16] = f2bf(acc[mi][ni][r] + cb[ni]);
    }
  }
}

// ---------------------------------------------------------------------------
// K4: persistent LSTM recurrence. 64 blocks x 256 threads (4 waves).
// Block j owns hidden units j*8..j*8+8 (32 packed gate rows held in VGPRs).
// Wave w owns batches w*16..w*16+16 (both M-tiles).
// Per step: MFMA gates from h broadcast (double-buffered, frag-ordered),
// lane-local i/f/g/o (C-layout reg = gate), flag handshake with agent fences.
__global__ __launch_bounds__(256, 1)
void k_rnn(const short* __restrict__ xproj, const short* __restrict__ Whp,
           const int* __restrict__ xlen, short* hbuf, int* flags,
           float* __restrict__ out) {
  const int j = blockIdx.x;       // 64
  const int tid = threadIdx.x;
  const int w = tid >> 6;
  const int lane = tid & 63;
  const int lr = lane & 15, lg = lane >> 4;
  const int batch = w * 16 + lr;
  const int mylen = xlen[batch];

  // Preload W_hh slice as A-fragments (held in VGPRs for all 512 steps)
  bf16x8 Af0[16], Af1[16];
  {
    const short* wp = Whp + (size_t)j * 32 * 512;
    #pragma unroll
    for (int kk = 0; kk < 16; ++kk) {
      Af0[kk] = *(const bf16x8*)(wp + (size_t)lr * 512 + kk * 32 + lg * 8);
      Af1[kk] = *(const bf16x8*)(wp + (size_t)(16 + lr) * 512 + kk * 32 + lg * 8);
    }
  }

  float c0 = 0.f, c1 = 0.f, h0 = 0.f, h1 = 0.f;
  const short* xbase = xproj + (size_t)batch * 512 * 2048 + j * 32 + lg * 4;
  float* outb = out + (size_t)batch * 512 * 512 + (size_t)j * 8 + lg;

  s16x4 xc0 = *(const s16x4*)(xbase);         // x for t=0, mt=0 (i,f,g,o)
  s16x4 xc1 = *(const s16x4*)(xbase + 16);    // mt=1

  #pragma unroll 1
  for (int t = 0; t < 512; ++t) {
    f32x4 acc0 = {0.f, 0.f, 0.f, 0.f}, acc1 = {0.f, 0.f, 0.f, 0.f};
    if (t > 0) {
      // wait for all 64 producers to have published generation t-1
      while (true) {
        int v = __hip_atomic_load(flags + lane, __ATOMIC_RELAXED, __HIP_MEMORY_SCOPE_AGENT);
        if (__all(v >= t)) break;
        __builtin_amdgcn_s_sleep(1);
      }
      __builtin_amdgcn_fence(__ATOMIC_ACQUIRE, "agent");
      const short* hb = hbuf + (size_t)((t - 1) & 1) * (64 * 512);
      bf16x8 Bf[16];
      #pragma unroll
      for (int kk = 0; kk < 16; ++kk)
        Bf[kk] = *(const bf16x8*)(hb + ((kk * 4 + lg) * 64 + batch) * 8);
      #pragma unroll
      for (int kk = 0; kk < 16; ++kk) {
        acc0 = __builtin_amdgcn_mfma_f32_16x16x32_bf16(Af0[kk], Bf[kk], acc0, 0, 0, 0);
        acc1 = __builtin_amdgcn_mfma_f32_16x16x32_bf16(Af1[kk], Bf[kk], acc1, 0, 0, 0);
      }
    }
    // prefetch x(t+1) — overlaps MFMA wait / gate math / handshake
    const short* xp = xbase + (size_t)(t < 511 ? t + 1 : t) * 2048;
    s16x4 xn0 = *(const s16x4*)(xp);
    s16x4 xn1 = *(const s16x4*)(xp + 16);

    const bool m = (t < mylen);
    {  // mt = 0: unit = lg, regs = i,f,g,o
      float gi = acc0[0] + b2f(xc0[0]);
      float gf = acc0[1] + b2f(xc0[1]);
      float gg = acc0[2] + b2f(xc0[2]);
      float go = acc0[3] + b2f(xc0[3]);
      float ii = sigm_(gi), ff = sigm_(gf), gv = tanh_(gg), oo = sigm_(go);
      float cn = ff * c0 + ii * gv;
      float hn = oo * tanh_(cn);
      c0 = m ? cn : c0;
      h0 = m ? hn : h0;
      outb[(size_t)t * 512] = m ? hn : 0.0f;
    }
    {  // mt = 1: unit = 4 + lg
      float gi = acc1[0] + b2f(xc1[0]);
      float gf = acc1[1] + b2f(xc1[1]);
      float gg = acc1[2] + b2f(xc1[2]);
      float go = acc1[3] + b2f(xc1[3]);
      float ii = sigm_(gi), ff = sigm_(gf), gv = tanh_(gg), oo = sigm_(go);
      float cn = ff * c1 + ii * gv;
      float hn = oo * tanh_(cn);
      c1 = m ? cn : c1;
      h1 = m ? hn : h1;
      outb[(size_t)t * 512 + 4] = m ? hn : 0.0f;
    }
    // publish h slice in consumer fragment order: [hid>>3][batch][hid&7]
    short* hp = hbuf + (size_t)(t & 1) * (64 * 512) + ((size_t)j * 64 + batch) * 8;
    hp[lg] = f2bf(h0);
    hp[4 + lg] = f2bf(h1);
    __syncthreads();
    if (tid == 0) {
      __builtin_amdgcn_fence(__ATOMIC_RELEASE, "agent");
      __hip_atomic_store(flags + j, t + 1, __ATOMIC_RELAXED, __HIP_MEMORY_SCOPE_AGENT);
    }
    xc0 = xn0; xc1 = xn1;
  }
  // final hidden state hT -> out[B*L*D + batch*512 + hid]
  float* oh = out + (size_t)64 * 512 * 512 + (size_t)batch * 512 + j * 8;
  oh[lg] = h0;
  oh[4 + lg] = h1;
}

// ---------------------------------------------------------------------------
extern "C" void kernel_launch(void* const* d_in, const int* in_sizes, int n_in,
                              void* d_out, int out_size, void* d_ws, size_t ws_size,
                              hipStream_t stream) {
  const int*   X      = (const int*)d_in[0];
  const int*   Xlen   = (const int*)d_in[1];
  const int*   aspect = (const int*)d_in[2];
  const int*   alen   = (const int*)d_in[3];
  const float* emb    = (const float*)d_in[4];
  const float* W_ih   = (const float*)d_in[5];
  const float* W_hh   = (const float*)d_in[6];
  const float* b_ih   = (const float*)d_in[7];
  const float* b_hh   = (const float*)d_in[8];
  float* out = (float*)d_out;

  char* ws = (char*)d_ws;
  // offsets (bytes), all 4KB-aligned
  float* asp_emb = (float*)(ws + 0);           //   131072
  float* aspc    = (float*)(ws + 131072);      //   524288
  short* W1p     = (short*)(ws + 655360);      //  2097152
  short* Whp     = (short*)(ws + 2752512);     //  2097152
  short* hbuf    = (short*)(ws + 4849664);     //   131072
  int*   flags   = (int*)  (ws + 4980736);     //     4096
  short* word    = (short*)(ws + 4984832);     // 33554432
  short* xproj   = (short*)(ws + 38539264);    // 134217728  (total ~165MB)

  float* out_hT  = out + (size_t)64 * 512 * 512;            // (1,B,D)
  float* out_asp = out_hT + (size_t)64 * 512;               // (B,D)

  hipLaunchKernelGGL(k_asp,    dim3(64),        dim3(128), 0, stream,
                     aspect, alen, emb, asp_emb, out_asp, flags);
  hipLaunchKernelGGL(k_pack,   dim3(2048),      dim3(128), 0, stream,
                     W_ih, W_hh, W1p, Whp);
  hipLaunchKernelGGL(k_aspc,   dim3(64),        dim3(256), 0, stream,
                     asp_emb, W_ih, b_ih, b_hh, aspc);
  hipLaunchKernelGGL(k_gather, dim3(16384),     dim3(256), 0, stream,
                     X, Xlen, emb, word);
  hipLaunchKernelGGL(k_gemm,   dim3(256, 16),   dim3(256), 0, stream,
                     word, W1p, aspc, Xlen, xproj);
  hipLaunchKernelGGL(k_rnn,    dim3(64),        dim3(256), 0, stream,
                     xproj, Whp, Xlen, hbuf, flags, out);
}

// Round 2
// 4141.526 us; speedup vs baseline: 1.3924x; 1.3924x over previous
//
#include <hip/hip_runtime.h>

// ATAE-LSTM fused pipeline for MI355X (gfx950).
// V=50000, D=512, B=64, L=512, A=4, 4D=2048.

using f32x4  = __attribute__((ext_vector_type(4))) float;
using s16x4  = __attribute__((ext_vector_type(4))) short;
using bf16x8 = __attribute__((ext_vector_type(8))) __bf16;

#define LOG2E 1.4426950408889634f

__device__ __forceinline__ float b2f(short s) {
  union { unsigned u; float f; } c;
  c.u = ((unsigned)(unsigned short)s) << 16;
  return c.f;
}
__device__ __forceinline__ short f2bf(float f) {
  union { float f; unsigned u; } c; c.f = f;
  unsigned r = (c.u + 0x7FFFu + ((c.u >> 16) & 1u)) >> 16;
  return (short)(unsigned short)r;
}
__device__ __forceinline__ float sigm_(float x) {
  float e = __builtin_amdgcn_exp2f(-x * LOG2E);
  return __builtin_amdgcn_rcpf(1.0f + e);
}
__device__ __forceinline__ float tanh_(float x) {
  float e = __builtin_amdgcn_exp2f(x * (2.0f * LOG2E));
  return 1.0f - 2.0f * __builtin_amdgcn_rcpf(1.0f + e);
}

// ---------------------------------------------------------------------------
// K1a: aspect embedding average; also zeroes the 256 sync flags.
__global__ void k_asp(const int* __restrict__ aspect, const int* __restrict__ alen,
                      const float* __restrict__ emb, float* __restrict__ asp_emb,
                      float* __restrict__ out_asp, int* __restrict__ flags) {
  int b = blockIdx.x;          // 64
  int t = threadIdx.x;         // 128, 4 floats each
  if (b == 0) { flags[t] = 0; flags[128 + t] = 0; }
  f32x4 s = {0.f, 0.f, 0.f, 0.f};
  #pragma unroll
  for (int a = 0; a < 4; ++a) {
    int idx = aspect[b * 4 + a];
    s += *(const f32x4*)(emb + (size_t)idx * 512 + t * 4);
  }
  float inv = 1.0f / (float)alen[b];
  s[0] *= inv; s[1] *= inv; s[2] *= inv; s[3] *= inv;
  *(f32x4*)(asp_emb + (size_t)b * 512 + t * 4) = s;
  *(f32x4*)(out_asp + (size_t)b * 512 + t * 4) = s;
}

// ---------------------------------------------------------------------------
// K1b: pack W_ih (word half) and W_hh rows into block-interleaved gate order,
// bf16.  Packed row P: j=P>>5 (block), u=(P>>2)&7 (unit), gate=P&3;
// source gate row gr = gate*512 + j*8 + u.
// Whp ONLY: K-columns permuted within each 8-group (slot r <- unit
// (r>>1)+(r&1)*4) so the per-thread packed-u32 h publish order matches the
// MFMA B-fragment K order.
__global__ void k_pack(const float* __restrict__ W_ih, const float* __restrict__ W_hh,
                       short* __restrict__ W1p, short* __restrict__ Whp) {
  int P = blockIdx.x;          // 2048
  int t = threadIdx.x;         // 128, 4 elems each
  int gr = (P & 3) * 512 + (P >> 5) * 8 + ((P >> 2) & 7);
  f32x4 w1 = *(const f32x4*)(W_ih + (size_t)gr * 1024 + t * 4);
  s16x4 o1, oh;
  #pragma unroll
  for (int i = 0; i < 4; ++i) {
    o1[i] = f2bf(w1[i]);
    int c = t * 4 + i;
    int ks = (c & ~7) | (((c & 1) << 2) | ((c >> 1) & 3));
    oh[i] = f2bf(W_hh[(size_t)gr * 512 + ks]);
  }
  *(s16x4*)(W1p + (size_t)P * 512 + t * 4) = o1;
  *(s16x4*)(Whp + (size_t)P * 512 + t * 4) = oh;
}

// ---------------------------------------------------------------------------
// K1c: asp_contrib[b][P] = asp_emb[b] . W_ih[gr][512:1024] + b_ih[gr] + b_hh[gr]
__global__ void k_aspc(const float* __restrict__ asp_emb, const float* __restrict__ W_ih,
                       const float* __restrict__ b_ih, const float* __restrict__ b_hh,
                       float* __restrict__ aspc) {
  int tid = threadIdx.x;                 // 256
  int P = blockIdx.x * 32 + (tid >> 3);  // 64 blocks
  int gr = (P & 3) * 512 + (P >> 5) * 8 + ((P >> 2) & 7);
  const float* wrow = W_ih + (size_t)gr * 1024 + 512;
  float bias = b_ih[gr] + b_hh[gr];
  int b0 = (tid & 7) * 8;
  float a[8];
  #pragma unroll
  for (int i = 0; i < 8; ++i) a[i] = 0.f;
  for (int k = 0; k < 512; k += 4) {
    f32x4 wv = *(const f32x4*)(wrow + k);
    #pragma unroll
    for (int bb = 0; bb < 8; ++bb) {
      f32x4 av = *(const f32x4*)(asp_emb + (size_t)(b0 + bb) * 512 + k);
      a[bb] += wv[0] * av[0] + wv[1] * av[1] + wv[2] * av[2] + wv[3] * av[3];
    }
  }
  #pragma unroll
  for (int bb = 0; bb < 8; ++bb) aspc[(size_t)(b0 + bb) * 2048 + P] = a[bb] + bias;
}

// ---------------------------------------------------------------------------
// K2: word embedding gather -> bf16, zero masked rows.
__global__ void k_gather(const int* __restrict__ X, const int* __restrict__ xlen,
                         const float* __restrict__ emb, short* __restrict__ word) {
  int g = blockIdx.x * 256 + threadIdx.x;  // 16384 blocks
  int row = g >> 7;                        // 128 threads per row
  int k4 = (g & 127) << 2;
  int b = row >> 9, l = row & 511;
  s16x4 o;
  if (l < xlen[b]) {
    int idx = X[row];
    f32x4 v = *(const f32x4*)(emb + (size_t)idx * 512 + k4);
    o[0] = f2bf(v[0]); o[1] = f2bf(v[1]); o[2] = f2bf(v[2]); o[3] = f2bf(v[3]);
  } else {
    o[0] = 0; o[1] = 0; o[2] = 0; o[3] = 0;
  }
  *(s16x4*)(word + (size_t)row * 512 + k4) = o;
}

// ---------------------------------------------------------------------------
// K3: GEMM  xproj[(b,l)][P] = word[(b,l),:] . W1p[P,:] + aspc[b][P]   (bf16 out)
__global__ __launch_bounds__(256)
void k_gemm(const short* __restrict__ A, const short* __restrict__ B,
            const float* __restrict__ aspc, const int* __restrict__ xlen,
            short* __restrict__ C) {
  __shared__ char smem[65536];  // A0 A1 B0 B1, 16KB each
  const int rt = blockIdx.x, ct = blockIdx.y;
  const int b = rt >> 2;
  if (xlen[b] <= ((rt & 3) << 7)) return;  // fully-masked row tile
  const int tid = threadIdx.x;
  const int w = tid >> 6, lane = tid & 63;
  const int lr = lane & 15, lg = lane >> 4;
  const int wr = (w & 1) * 64, wc = (w >> 1) * 64;
  const char* Ab = (const char*)(A + (size_t)rt * 128 * 512);
  const char* Bb = (const char*)(B + (size_t)ct * 128 * 512);

  f32x4 acc[4][4];
  #pragma unroll
  for (int mi = 0; mi < 4; ++mi)
    #pragma unroll
    for (int ni = 0; ni < 4; ++ni) acc[mi][ni] = {0.f, 0.f, 0.f, 0.f};

  auto stage = [&](int kt, int buf) {
    #pragma unroll
    for (int p = 0; p < 4; ++p) {
      int dbase = w * 1024 + p * 4096;   // wave-uniform LDS base
      int d = dbase + (lane << 4);
      int row = d >> 7;
      int kb = (d & 127) ^ (((d >> 9) & 1) << 5);  // pre-swizzled source
      __builtin_amdgcn_global_load_lds(
          (const __attribute__((address_space(1))) unsigned*)(Ab + (size_t)row * 1024 + kt * 128 + kb),
          (__attribute__((address_space(3))) unsigned*)(smem + buf * 16384 + dbase), 16, 0, 0);
      __builtin_amdgcn_global_load_lds(
          (const __attribute__((address_space(1))) unsigned*)(Bb + (size_t)row * 1024 + kt * 128 + kb),
          (__attribute__((address_space(3))) unsigned*)(smem + 32768 + buf * 16384 + dbase), 16, 0, 0);
    }
  };

  stage(0, 0);
  __syncthreads();
  #pragma unroll 1
  for (int kt = 0; kt < 8; ++kt) {
    int cur = kt & 1;
    if (kt < 7) stage(kt + 1, cur ^ 1);
    const char* sAc = smem + cur * 16384;
    const char* sBc = smem + 32768 + cur * 16384;
    #pragma unroll
    for (int kk = 0; kk < 2; ++kk) {
      bf16x8 af[4], bfr[4];
      #pragma unroll
      for (int mi = 0; mi < 4; ++mi) {
        int lin = (wr + mi * 16 + lr) * 128 + kk * 64 + lg * 16;
        af[mi] = *(const bf16x8*)(sAc + (lin ^ (((lin >> 9) & 1) << 5)));
      }
      #pragma unroll
      for (int ni = 0; ni < 4; ++ni) {
        int lin = (wc + ni * 16 + lr) * 128 + kk * 64 + lg * 16;
        bfr[ni] = *(const bf16x8*)(sBc + (lin ^ (((lin >> 9) & 1) << 5)));
      }
      #pragma unroll
      for (int mi = 0; mi < 4; ++mi)
        #pragma unroll
        for (int ni = 0; ni < 4; ++ni)
          acc[mi][ni] = __builtin_amdgcn_mfma_f32_16x16x32_bf16(af[mi], bfr[ni], acc[mi][ni], 0, 0, 0);
    }
    __syncthreads();
  }

  const int colb = ct * 128 + wc;
  float cb[4];
  #pragma unroll
  for (int ni = 0; ni < 4; ++ni) cb[ni] = aspc[(size_t)b * 2048 + colb + ni * 16 + lr];
  #pragma unroll
  for (int mi = 0; mi < 4; ++mi) {
    const int row0 = rt * 128 + wr + mi * 16 + lg * 4;
    #pragma unroll
    for (int r = 0; r < 4; ++r) {
      short* crow = C + (size_t)(row0 + r) * 2048 + colb + lr;
      #pragma unroll
      for (int ni = 0; ni < 4; ++ni)
        crow[ni * 16] = f2bf(acc[mi][ni][r] + cb[ni]);
    }
  }
}

// ---------------------------------------------------------------------------
// K4: persistent LSTM recurrence, fence-free L3 message passing.
// 64 blocks x 4 waves. Block j owns hidden units j*8..j*8+8 (weights pinned
// in VGPRs). Wave w owns batches w*16..w*16+16 and syncs ONLY with wave-w
// producers via per-wave flags (relaxed agent atomics; no __syncthreads,
// no cache-maintenance fences).
__global__ __launch_bounds__(256, 1)
void k_rnn(const short* __restrict__ xproj, const short* __restrict__ Whp,
           const int* __restrict__ xlen, unsigned* hbuf, int* flags,
           float* __restrict__ out) {
  const int j = blockIdx.x;       // 64
  const int tid = threadIdx.x;
  const int w = tid >> 6;
  const int lane = tid & 63;
  const int lr = lane & 15, lg = lane >> 4;
  const int batch = w * 16 + lr;
  const int mylen = xlen[batch];

  // block-uniform max sequence length (same value in every block)
  int nt = xlen[lane];
  #pragma unroll
  for (int d = 32; d; d >>= 1) nt = max(nt, __shfl_xor(nt, d));

  // Preload W_hh slice as A-fragments; pin in VGPRs (compiler sank these
  // into the loop in R1: VGPR_Count was 88 < the 128 the frags need).
  f32x4 Af0[16], Af1[16];
  {
    const short* wp = Whp + (size_t)j * 32 * 512;
    #pragma unroll
    for (int kk = 0; kk < 16; ++kk) {
      Af0[kk] = *(const f32x4*)(wp + (size_t)lr * 512 + kk * 32 + lg * 8);
      Af1[kk] = *(const f32x4*)(wp + (size_t)(16 + lr) * 512 + kk * 32 + lg * 8);
    }
    #pragma unroll
    for (int kk = 0; kk < 16; ++kk)
      asm volatile("" : "+v"(Af0[kk]), "+v"(Af1[kk]));
  }

  float c0 = 0.f, c1 = 0.f, h0 = 0.f, h1 = 0.f;
  const short* xbase = xproj + (size_t)batch * 512 * 2048 + j * 32 + lg * 4;
  float* outb = out + (size_t)batch * 512 * 512 + (size_t)j * 8 + lg;
  int* myflag = flags + (w << 6) + j;
  const int pollbase = w << 6;

  s16x4 xc0 = *(const s16x4*)(xbase);         // x for t=0, mt=0 (i,f,g,o)
  s16x4 xc1 = *(const s16x4*)(xbase + 16);    // mt=1

  #pragma unroll 1
  for (int t = 0; t < nt; ++t) {
    f32x4 acc0 = {0.f, 0.f, 0.f, 0.f}, acc1 = {0.f, 0.f, 0.f, 0.f};
    if (t > 0) {
      // wait for all wave-w producers to have published generation t-1
      while (true) {
        int v = __hip_atomic_load(flags + pollbase + lane, __ATOMIC_RELAXED,
                                  __HIP_MEMORY_SCOPE_AGENT);
        if (__all(v >= t)) break;
        __builtin_amdgcn_s_sleep(1);
      }
      asm volatile("" ::: "memory");
      const unsigned long long* hb = (const unsigned long long*)
          (hbuf + (size_t)((t - 1) & 1) * 16384);
      bf16x8 Bf[16];
      #pragma unroll
      for (int kk = 0; kk < 16; ++kk) {
        size_t bi = ((size_t)((kk * 4 + lg) * 64 + batch)) * 2;
        union { unsigned long long q[2]; bf16x8 v; } u;
        u.q[0] = __hip_atomic_load(hb + bi, __ATOMIC_RELAXED, __HIP_MEMORY_SCOPE_AGENT);
        u.q[1] = __hip_atomic_load(hb + bi + 1, __ATOMIC_RELAXED, __HIP_MEMORY_SCOPE_AGENT);
        Bf[kk] = u.v;
      }
      #pragma unroll
      for (int kk = 0; kk < 16; ++kk) {
        acc0 = __builtin_amdgcn_mfma_f32_16x16x32_bf16(
            __builtin_bit_cast(bf16x8, Af0[kk]), Bf[kk], acc0, 0, 0, 0);
        acc1 = __builtin_amdgcn_mfma_f32_16x16x32_bf16(
            __builtin_bit_cast(bf16x8, Af1[kk]), Bf[kk], acc1, 0, 0, 0);
      }
    }

    const bool m = (t < mylen);
    float hn0, hn1;
    {  // mt = 0: unit = lg, regs = i,f,g,o
      float gi = acc0[0] + b2f(xc0[0]);
      float gf = acc0[1] + b2f(xc0[1]);
      float gg = acc0[2] + b2f(xc0[2]);
      float go = acc0[3] + b2f(xc0[3]);
      float ii = sigm_(gi), ff = sigm_(gf), gv = tanh_(gg), oo = sigm_(go);
      float cn = ff * c0 + ii * gv;
      hn0 = oo * tanh_(cn);
      c0 = m ? cn : c0;
      h0 = m ? hn0 : h0;
    }
    {  // mt = 1: unit = 4 + lg
      float gi = acc1[0] + b2f(xc1[0]);
      float gf = acc1[1] + b2f(xc1[1]);
      float gg = acc1[2] + b2f(xc1[2]);
      float go = acc1[3] + b2f(xc1[3]);
      float ii = sigm_(gi), ff = sigm_(gf), gv = tanh_(gg), oo = sigm_(go);
      float cn = ff * c1 + ii * gv;
      hn1 = oo * tanh_(cn);
      c1 = m ? cn : c1;
      h1 = m ? hn1 : h1;
    }

    // publish h pair (units lg, lg+4 of this batch) as one packed u32 to L3
    unsigned pk = (unsigned)(unsigned short)f2bf(h0)
                | ((unsigned)(unsigned short)f2bf(h1) << 16);
    unsigned* hw = hbuf + (size_t)(t & 1) * 16384 + ((j * 64 + batch) * 4 + lg);
    __hip_atomic_store(hw, pk, __ATOMIC_RELAXED, __HIP_MEMORY_SCOPE_AGENT);
    asm volatile("s_waitcnt vmcnt(0)" ::: "memory");  // h at L3 before flag
    if (lane == 0)
      __hip_atomic_store(myflag, t + 1, __ATOMIC_RELAXED, __HIP_MEMORY_SCOPE_AGENT);

    // sequence output (masked rows are zero), then next-x prefetch
    outb[(size_t)t * 512] = m ? hn0 : 0.0f;
    outb[(size_t)t * 512 + 4] = m ? hn1 : 0.0f;
    int tn = (t + 1 < nt) ? t + 1 : t;
    const short* xp = xbase + (size_t)tn * 2048;
    xc0 = *(const s16x4*)(xp);
    xc1 = *(const s16x4*)(xp + 16);
  }

  // zero tail of the sequence output (t >= nt >= all xlen)
  for (int t = nt; t < 512; ++t) {
    outb[(size_t)t * 512] = 0.0f;
    outb[(size_t)t * 512 + 4] = 0.0f;
  }

  // final hidden state hT -> out[B*L*D + batch*512 + hid]
  float* oh = out + (size_t)64 * 512 * 512 + (size_t)batch * 512 + j * 8;
  oh[lg] = h0;
  oh[4 + lg] = h1;
}

// ---------------------------------------------------------------------------
extern "C" void kernel_launch(void* const* d_in, const int* in_sizes, int n_in,
                              void* d_out, int out_size, void* d_ws, size_t ws_size,
                              hipStream_t stream) {
  const int*   X      = (const int*)d_in[0];
  const int*   Xlen   = (const int*)d_in[1];
  const int*   aspect = (const int*)d_in[2];
  const int*   alen   = (const int*)d_in[3];
  const float* emb    = (const float*)d_in[4];
  const float* W_ih   = (const float*)d_in[5];
  const float* W_hh   = (const float*)d_in[6];
  const float* b_ih   = (const float*)d_in[7];
  const float* b_hh   = (const float*)d_in[8];
  float* out = (float*)d_out;

  char* ws = (char*)d_ws;
  // offsets (bytes), all 4KB-aligned
  float*    asp_emb = (float*)(ws + 0);           //   131072
  float*    aspc    = (float*)(ws + 131072);      //   524288
  short*    W1p     = (short*)(ws + 655360);      //  2097152
  short*    Whp     = (short*)(ws + 2752512);     //  2097152
  unsigned* hbuf    = (unsigned*)(ws + 4849664);  //   131072 (2 gens x 16384 u32)
  int*      flags   = (int*)  (ws + 4980736);     //     4096 (256 used)
  short*    word    = (short*)(ws + 4984832);     // 33554432
  short*    xproj   = (short*)(ws + 38539264);    // 134217728  (total ~165MB)

  float* out_hT  = out + (size_t)64 * 512 * 512;            // (1,B,D)
  float* out_asp = out_hT + (size_t)64 * 512;               // (B,D)

  hipLaunchKernelGGL(k_asp,    dim3(64),        dim3(128), 0, stream,
                     aspect, alen, emb, asp_emb, out_asp, flags);
  hipLaunchKernelGGL(k_pack,   dim3(2048),      dim3(128), 0, stream,
                     W_ih, W_hh, W1p, Whp);
  hipLaunchKernelGGL(k_aspc,   dim3(64),        dim3(256), 0, stream,
                     asp_emb, W_ih, b_ih, b_hh, aspc);
  hipLaunchKernelGGL(k_gather, dim3(16384),     dim3(256), 0, stream,
                     X, Xlen, emb, word);
  hipLaunchKernelGGL(k_gemm,   dim3(256, 16),   dim3(256), 0, stream,
                     word, W1p, aspc, Xlen, xproj);
  hipLaunchKernelGGL(k_rnn,    dim3(64),        dim3(256), 0, stream,
                     xproj, Whp, Xlen, hbuf, flags, out);
}

// Round 3
// 3457.458 us; speedup vs baseline: 1.6679x; 1.1979x over previous
//
#include <hip/hip_runtime.h>

// ATAE-LSTM fused pipeline for MI355X (gfx950).
// V=50000, D=512, B=64, L=512, A=4, 4D=2048.

using f32x4  = __attribute__((ext_vector_type(4))) float;
using s16x4  = __attribute__((ext_vector_type(4))) short;
using bf16x8 = __attribute__((ext_vector_type(8))) __bf16;

#define LOG2E 1.4426950408889634f

__device__ __forceinline__ float b2f(short s) {
  union { unsigned u; float f; } c;
  c.u = ((unsigned)(unsigned short)s) << 16;
  return c.f;
}
__device__ __forceinline__ short f2bf(float f) {
  union { float f; unsigned u; } c; c.f = f;
  unsigned r = (c.u + 0x7FFFu + ((c.u >> 16) & 1u)) >> 16;
  return (short)(unsigned short)r;
}
__device__ __forceinline__ float sigm_(float x) {
  float e = __builtin_amdgcn_exp2f(-x * LOG2E);
  return __builtin_amdgcn_rcpf(1.0f + e);
}
__device__ __forceinline__ float tanh_(float x) {
  float e = __builtin_amdgcn_exp2f(x * (2.0f * LOG2E));
  return 1.0f - 2.0f * __builtin_amdgcn_rcpf(1.0f + e);
}

// ---------------------------------------------------------------------------
// K1a: aspect embedding average; also zeroes hbuf (tags must start at 0 for
// every launch -> graph-replay deterministic).
__global__ void k_asp(const int* __restrict__ aspect, const int* __restrict__ alen,
                      const float* __restrict__ emb, float* __restrict__ asp_emb,
                      float* __restrict__ out_asp, unsigned* __restrict__ hbuf) {
  int b = blockIdx.x;          // 64
  int t = threadIdx.x;         // 128, 4 floats each
  {
    unsigned* hz = hbuf + (size_t)(b * 128 + t) * 8;  // 8192 thr x 8 u32 = 256KB
    #pragma unroll
    for (int i = 0; i < 8; ++i) hz[i] = 0u;
  }
  f32x4 s = {0.f, 0.f, 0.f, 0.f};
  #pragma unroll
  for (int a = 0; a < 4; ++a) {
    int idx = aspect[b * 4 + a];
    s += *(const f32x4*)(emb + (size_t)idx * 512 + t * 4);
  }
  float inv = 1.0f / (float)alen[b];
  s[0] *= inv; s[1] *= inv; s[2] *= inv; s[3] *= inv;
  *(f32x4*)(asp_emb + (size_t)b * 512 + t * 4) = s;
  *(f32x4*)(out_asp + (size_t)b * 512 + t * 4) = s;
}

// ---------------------------------------------------------------------------
// K1b: pack W_ih (word half) and W_hh rows into block-interleaved gate order,
// bf16.  Packed row P: j=P>>5 (block), u=(P>>2)&7 (unit), gate=P&3;
// source gate row gr = gate*512 + j*8 + u.  K-columns identity (unit order).
__global__ void k_pack(const float* __restrict__ W_ih, const float* __restrict__ W_hh,
                       short* __restrict__ W1p, short* __restrict__ Whp) {
  int P = blockIdx.x;          // 2048
  int t = threadIdx.x;         // 128, 4 elems each
  int gr = (P & 3) * 512 + (P >> 5) * 8 + ((P >> 2) & 7);
  f32x4 w1 = *(const f32x4*)(W_ih + (size_t)gr * 1024 + t * 4);
  f32x4 wh = *(const f32x4*)(W_hh + (size_t)gr * 512 + t * 4);
  s16x4 o1, oh;
  #pragma unroll
  for (int i = 0; i < 4; ++i) { o1[i] = f2bf(w1[i]); oh[i] = f2bf(wh[i]); }
  *(s16x4*)(W1p + (size_t)P * 512 + t * 4) = o1;
  *(s16x4*)(Whp + (size_t)P * 512 + t * 4) = oh;
}

// ---------------------------------------------------------------------------
// K1c: asp_contrib[b][P] = asp_emb[b] . W_ih[gr][512:1024] + b_ih[gr] + b_hh[gr]
__global__ void k_aspc(const float* __restrict__ asp_emb, const float* __restrict__ W_ih,
                       const float* __restrict__ b_ih, const float* __restrict__ b_hh,
                       float* __restrict__ aspc) {
  int tid = threadIdx.x;                 // 256
  int P = blockIdx.x * 32 + (tid >> 3);  // 64 blocks
  int gr = (P & 3) * 512 + (P >> 5) * 8 + ((P >> 2) & 7);
  const float* wrow = W_ih + (size_t)gr * 1024 + 512;
  float bias = b_ih[gr] + b_hh[gr];
  int b0 = (tid & 7) * 8;
  float a[8];
  #pragma unroll
  for (int i = 0; i < 8; ++i) a[i] = 0.f;
  for (int k = 0; k < 512; k += 4) {
    f32x4 wv = *(const f32x4*)(wrow + k);
    #pragma unroll
    for (int bb = 0; bb < 8; ++bb) {
      f32x4 av = *(const f32x4*)(asp_emb + (size_t)(b0 + bb) * 512 + k);
      a[bb] += wv[0] * av[0] + wv[1] * av[1] + wv[2] * av[2] + wv[3] * av[3];
    }
  }
  #pragma unroll
  for (int bb = 0; bb < 8; ++bb) aspc[(size_t)(b0 + bb) * 2048 + P] = a[bb] + bias;
}

// ---------------------------------------------------------------------------
// K2: word embedding gather -> bf16, zero masked rows.
__global__ void k_gather(const int* __restrict__ X, const int* __restrict__ xlen,
                         const float* __restrict__ emb, short* __restrict__ word) {
  int g = blockIdx.x * 256 + threadIdx.x;  // 16384 blocks
  int row = g >> 7;                        // 128 threads per row
  int k4 = (g & 127) << 2;
  int b = row >> 9, l = row & 511;
  s16x4 o;
  if (l < xlen[b]) {
    int idx = X[row];
    f32x4 v = *(const f32x4*)(emb + (size_t)idx * 512 + k4);
    o[0] = f2bf(v[0]); o[1] = f2bf(v[1]); o[2] = f2bf(v[2]); o[3] = f2bf(v[3]);
  } else {
    o[0] = 0; o[1] = 0; o[2] = 0; o[3] = 0;
  }
  *(s16x4*)(word + (size_t)row * 512 + k4) = o;
}

// ---------------------------------------------------------------------------
// K3: GEMM  xproj[(b,l)][P] = word[(b,l),:] . W1p[P,:] + aspc[b][P]   (bf16 out)
__global__ __launch_bounds__(256)
void k_gemm(const short* __restrict__ A, const short* __restrict__ B,
            const float* __restrict__ aspc, const int* __restrict__ xlen,
            short* __restrict__ C) {
  __shared__ char smem[65536];  // A0 A1 B0 B1, 16KB each
  const int rt = blockIdx.x, ct = blockIdx.y;
  const int b = rt >> 2;
  if (xlen[b] <= ((rt & 3) << 7)) return;  // fully-masked row tile
  const int tid = threadIdx.x;
  const int w = tid >> 6, lane = tid & 63;
  const int lr = lane & 15, lg = lane >> 4;
  const int wr = (w & 1) * 64, wc = (w >> 1) * 64;
  const char* Ab = (const char*)(A + (size_t)rt * 128 * 512);
  const char* Bb = (const char*)(B + (size_t)ct * 128 * 512);

  f32x4 acc[4][4];
  #pragma unroll
  for (int mi = 0; mi < 4; ++mi)
    #pragma unroll
    for (int ni = 0; ni < 4; ++ni) acc[mi][ni] = {0.f, 0.f, 0.f, 0.f};

  auto stage = [&](int kt, int buf) {
    #pragma unroll
    for (int p = 0; p < 4; ++p) {
      int dbase = w * 1024 + p * 4096;   // wave-uniform LDS base
      int d = dbase + (lane << 4);
      int row = d >> 7;
      int kb = (d & 127) ^ (((d >> 9) & 1) << 5);  // pre-swizzled source
      __builtin_amdgcn_global_load_lds(
          (const __attribute__((address_space(1))) unsigned*)(Ab + (size_t)row * 1024 + kt * 128 + kb),
          (__attribute__((address_space(3))) unsigned*)(smem + buf * 16384 + dbase), 16, 0, 0);
      __builtin_amdgcn_global_load_lds(
          (const __attribute__((address_space(1))) unsigned*)(Bb + (size_t)row * 1024 + kt * 128 + kb),
          (__attribute__((address_space(3))) unsigned*)(smem + 32768 + buf * 16384 + dbase), 16, 0, 0);
    }
  };

  stage(0, 0);
  __syncthreads();
  #pragma unroll 1
  for (int kt = 0; kt < 8; ++kt) {
    int cur = kt & 1;
    if (kt < 7) stage(kt + 1, cur ^ 1);
    const char* sAc = smem + cur * 16384;
    const char* sBc = smem + 32768 + cur * 16384;
    #pragma unroll
    for (int kk = 0; kk < 2; ++kk) {
      bf16x8 af[4], bfr[4];
      #pragma unroll
      for (int mi = 0; mi < 4; ++mi) {
        int lin = (wr + mi * 16 + lr) * 128 + kk * 64 + lg * 16;
        af[mi] = *(const bf16x8*)(sAc + (lin ^ (((lin >> 9) & 1) << 5)));
      }
      #pragma unroll
      for (int ni = 0; ni < 4; ++ni) {
        int lin = (wc + ni * 16 + lr) * 128 + kk * 64 + lg * 16;
        bfr[ni] = *(const bf16x8*)(sBc + (lin ^ (((lin >> 9) & 1) << 5)));
      }
      #pragma unroll
      for (int mi = 0; mi < 4; ++mi)
        #pragma unroll
        for (int ni = 0; ni < 4; ++ni)
          acc[mi][ni] = __builtin_amdgcn_mfma_f32_16x16x32_bf16(af[mi], bfr[ni], acc[mi][ni], 0, 0, 0);
    }
    __syncthreads();
  }

  const int colb = ct * 128 + wc;
  float cb[4];
  #pragma unroll
  for (int ni = 0; ni < 4; ++ni) cb[ni] = aspc[(size_t)b * 2048 + colb + ni * 16 + lr];
  #pragma unroll
  for (int mi = 0; mi < 4; ++mi) {
    const int row0 = rt * 128 + wr + mi * 16 + lg * 4;
    #pragma unroll
    for (int r = 0; r < 4; ++r) {
      short* crow = C + (size_t)(row0 + r) * 2048 + colb + lr;
      #pragma unroll
      for (int ni = 0; ni < 4; ++ni)
        crow[ni * 16] = f2bf(acc[mi][ni][r] + cb[ni]);
    }
  }
}

// ---------------------------------------------------------------------------
// K4: persistent LSTM recurrence, self-tagged h exchange through L3.
// Each published dword = (bf16(h) << 16) | (t+1): per-dword atomicity makes
// the payload self-validating -> no flags, no store drains, no poll round
// trip. Weights live in LDS (XOR-swizzled, conflict-free ds_read_b128).
__global__ __launch_bounds__(256, 1)
void k_rnn(const short* __restrict__ xproj, const short* __restrict__ Whp,
           const int* __restrict__ xlen, unsigned* hbuf, float* __restrict__ out) {
  __shared__ char wlds[32768];
  const int j = blockIdx.x;       // 64
  const int tid = threadIdx.x;
  const int w = tid >> 6;
  const int lane = tid & 63;
  const int lr = lane & 15, lg = lane >> 4;
  const int batch = w * 16 + lr;
  const int mylen = xlen[batch];

  // block-uniform max sequence length
  int nt = xlen[lane];
  #pragma unroll
  for (int d = 32; d; d >>= 1) nt = max(nt, __shfl_xor(nt, d));

  // stage this block's W_hh slice (32 packed rows x 512 cols bf16 = 32KB)
  // into LDS with byte-XOR swizzle (row&7)<<4 to kill the stride-1024
  // bank conflict on fragment reads.
  {
    const char* src = (const char*)(Whp + (size_t)j * 32 * 512);
    int base = tid * 128;
    int row = base >> 10;
    int c0 = base & 1023;
    #pragma unroll
    for (int i = 0; i < 8; ++i) {
      int c = c0 + i * 16;
      *(f32x4*)(wlds + row * 1024 + (c ^ ((row & 7) << 4))) =
          *(const f32x4*)(src + (size_t)row * 1024 + c);
    }
  }
  __syncthreads();

  float cc0 = 0.f, cc1 = 0.f, h0 = 0.f, h1 = 0.f;
  const short* xbase = xproj + (size_t)batch * 512 * 2048 + j * 32 + lg * 4;
  float* outb = out + (size_t)batch * 512 * 512 + (size_t)j * 8 + lg;

  s16x4 xc0 = *(const s16x4*)(xbase);         // x for t=0, mt=0 (i,f,g,o)
  s16x4 xc1 = *(const s16x4*)(xbase + 16);    // mt=1

  #pragma unroll 1
  for (int t = 0; t < nt; ++t) {
    f32x4 acc0 = {0.f, 0.f, 0.f, 0.f}, acc1 = {0.f, 0.f, 0.f, 0.f};
    if (t > 0) {
      const unsigned* hb = hbuf + (size_t)((t - 1) & 1) * 32768 + batch * 512;
      const unsigned tneed = (unsigned)t;   // tag written at step t-1 is t
      bf16x8 Bf[16];
      int4 ta[16], tb[16];
      unsigned pend = 0xFFFFu;              // wave-uniform pending kk mask
      while (pend) {
        #pragma unroll
        for (int kk = 0; kk < 16; ++kk) {
          if (pend & (1u << kk)) {
            const unsigned* p = hb + kk * 32 + lg * 8;
            asm volatile("global_load_dwordx4 %0, %1, off sc0 sc1"
                         : "=&v"(ta[kk]) : "v"(p) : "memory");
            asm volatile("global_load_dwordx4 %0, %1, off sc0 sc1"
                         : "=&v"(tb[kk]) : "v"(p + 4) : "memory");
          }
        }
        asm volatile("s_waitcnt vmcnt(0)" ::: "memory");
        __builtin_amdgcn_sched_barrier(0);
        #pragma unroll
        for (int kk = 0; kk < 16; ++kk) {
          if (pend & (1u << kk)) {
            int4 q0 = ta[kk], q1 = tb[kk];
            unsigned m0 = min((unsigned)q0.x & 0xffffu, (unsigned)q0.y & 0xffffu);
            unsigned m1 = min((unsigned)q0.z & 0xffffu, (unsigned)q0.w & 0xffffu);
            unsigned m2 = min((unsigned)q1.x & 0xffffu, (unsigned)q1.y & 0xffffu);
            unsigned m3 = min((unsigned)q1.z & 0xffffu, (unsigned)q1.w & 0xffffu);
            unsigned mn = min(min(m0, m1), min(m2, m3));
            if (__all(mn >= tneed)) {
              union { unsigned u[4]; bf16x8 v; } pk;
              pk.u[0] = ((unsigned)q0.x >> 16) | ((unsigned)q0.y & 0xffff0000u);
              pk.u[1] = ((unsigned)q0.z >> 16) | ((unsigned)q0.w & 0xffff0000u);
              pk.u[2] = ((unsigned)q1.x >> 16) | ((unsigned)q1.y & 0xffff0000u);
              pk.u[3] = ((unsigned)q1.z >> 16) | ((unsigned)q1.w & 0xffff0000u);
              Bf[kk] = pk.v;
              pend &= ~(1u << kk);
            }
          }
        }
      }
      #pragma unroll
      for (int kk = 0; kk < 16; ++kk) {
        int sw = (kk * 64 + lg * 16) ^ ((lr & 7) << 4);
        bf16x8 a0 = *(const bf16x8*)(wlds + lr * 1024 + sw);
        bf16x8 a1 = *(const bf16x8*)(wlds + (16 + lr) * 1024 + sw);
        acc0 = __builtin_amdgcn_mfma_f32_16x16x32_bf16(a0, Bf[kk], acc0, 0, 0, 0);
        acc1 = __builtin_amdgcn_mfma_f32_16x16x32_bf16(a1, Bf[kk], acc1, 0, 0, 0);
      }
    }

    const bool m = (t < mylen);
    float hn0, hn1;
    {  // mt = 0: unit = lg, regs = i,f,g,o
      float gi = acc0[0] + b2f(xc0[0]);
      float gf = acc0[1] + b2f(xc0[1]);
      float gg = acc0[2] + b2f(xc0[2]);
      float go = acc0[3] + b2f(xc0[3]);
      float ii = sigm_(gi), ff = sigm_(gf), gv = tanh_(gg), oo = sigm_(go);
      float cn = ff * cc0 + ii * gv;
      hn0 = oo * tanh_(cn);
      cc0 = m ? cn : cc0;
      h0 = m ? hn0 : h0;
    }
    {  // mt = 1: unit = 4 + lg
      float gi = acc1[0] + b2f(xc1[0]);
      float gf = acc1[1] + b2f(xc1[1]);
      float gg = acc1[2] + b2f(xc1[2]);
      float go = acc1[3] + b2f(xc1[3]);
      float ii = sigm_(gi), ff = sigm_(gf), gv = tanh_(gg), oo = sigm_(go);
      float cn = ff * cc1 + ii * gv;
      hn1 = oo * tanh_(cn);
      cc1 = m ? cn : cc1;
      h1 = m ? hn1 : h1;
    }

    // fire-and-forget tagged publish: dword = (bf16(h)<<16) | (t+1)
    unsigned tag = (unsigned)(t + 1) & 0xffffu;
    unsigned d0 = ((unsigned)(unsigned short)f2bf(h0) << 16) | tag;
    unsigned d1 = ((unsigned)(unsigned short)f2bf(h1) << 16) | tag;
    unsigned* hw = hbuf + (size_t)(t & 1) * 32768 + batch * 512 + j * 8 + lg;
    __hip_atomic_store(hw, d0, __ATOMIC_RELAXED, __HIP_MEMORY_SCOPE_AGENT);
    __hip_atomic_store(hw + 4, d1, __ATOMIC_RELAXED, __HIP_MEMORY_SCOPE_AGENT);

    // sequence output, then next-x prefetch
    outb[(size_t)t * 512] = m ? hn0 : 0.0f;
    outb[(size_t)t * 512 + 4] = m ? hn1 : 0.0f;
    int tn = (t + 1 < nt) ? t + 1 : t;
    const short* xp = xbase + (size_t)tn * 2048;
    xc0 = *(const s16x4*)(xp);
    xc1 = *(const s16x4*)(xp + 16);
  }

  // zero tail of the sequence output (t >= nt >= all xlen)
  for (int t = nt; t < 512; ++t) {
    outb[(size_t)t * 512] = 0.0f;
    outb[(size_t)t * 512 + 4] = 0.0f;
  }

  // final hidden state hT -> out[B*L*D + batch*512 + hid]
  float* oh = out + (size_t)64 * 512 * 512 + (size_t)batch * 512 + j * 8;
  oh[lg] = h0;
  oh[4 + lg] = h1;
}

// ---------------------------------------------------------------------------
extern "C" void kernel_launch(void* const* d_in, const int* in_sizes, int n_in,
                              void* d_out, int out_size, void* d_ws, size_t ws_size,
                              hipStream_t stream) {
  const int*   X      = (const int*)d_in[0];
  const int*   Xlen   = (const int*)d_in[1];
  const int*   aspect = (const int*)d_in[2];
  const int*   alen   = (const int*)d_in[3];
  const float* emb    = (const float*)d_in[4];
  const float* W_ih   = (const float*)d_in[5];
  const float* W_hh   = (const float*)d_in[6];
  const float* b_ih   = (const float*)d_in[7];
  const float* b_hh   = (const float*)d_in[8];
  float* out = (float*)d_out;

  char* ws = (char*)d_ws;
  // offsets (bytes)
  float*    asp_emb = (float*)(ws + 0);           //    131072
  float*    aspc    = (float*)(ws + 131072);      //    524288
  short*    W1p     = (short*)(ws + 655360);      //   2097152
  short*    Whp     = (short*)(ws + 2752512);     //   2097152
  unsigned* hbuf    = (unsigned*)(ws + 4849664);  //    262144 (2 gens x 32768 u32, tagged)
  short*    word    = (short*)(ws + 5111808);     //  33554432
  short*    xproj   = (short*)(ws + 38666240);    // 134217728  (total ~165MB)

  float* out_hT  = out + (size_t)64 * 512 * 512;            // (1,B,D)
  float* out_asp = out_hT + (size_t)64 * 512;               // (B,D)

  hipLaunchKernelGGL(k_asp,    dim3(64),        dim3(128), 0, stream,
                     aspect, alen, emb, asp_emb, out_asp, hbuf);
  hipLaunchKernelGGL(k_pack,   dim3(2048),      dim3(128), 0, stream,
                     W_ih, W_hh, W1p, Whp);
  hipLaunchKernelGGL(k_aspc,   dim3(64),        dim3(256), 0, stream,
                     asp_emb, W_ih, b_ih, b_hh, aspc);
  hipLaunchKernelGGL(k_gather, dim3(16384),     dim3(256), 0, stream,
                     X, Xlen, emb, word);
  hipLaunchKernelGGL(k_gemm,   dim3(256, 16),   dim3(256), 0, stream,
                     word, W1p, aspc, Xlen, xproj);
  hipLaunchKernelGGL(k_rnn,    dim3(64),        dim3(256), 0, stream,
                     xproj, Whp, Xlen, hbuf, out);
}